// Round 1
// baseline (682.334 us; speedup 1.0000x reference)
//
#include <hip/hip_runtime.h>
#include <math.h>

// RANSAC homography (kornia-style) for MI355X.
// Inputs: kp1 (N=10000 x 2 f32), kp2 (N x 2 f32), idxs (B=2048 x 4 i32)
// Output: d_out = [model 3x3 f32 (9), inliers (N) as 0/1 f32] = 10009 floats.

struct Hdr {
  int best_idx;
  float best_score;
  int pad0, pad1;
  double nrm[6]; // mx1, my1, s1, mx2, my2, s2
};

__device__ __forceinline__ float sq_err9(const float h[9], float x1, float y1,
                                         float x2, float y2) {
  float px = h[0] * x1 + h[1] * y1 + h[2];
  float py = h[3] * x1 + h[4] * y1 + h[5];
  float pz = h[6] * x1 + h[7] * y1 + h[8];
  float s  = (fabsf(pz) > 1e-8f) ? (1.0f / pz) : 1.0f;
  float dx = px * s - x2;
  float dy = py * s - y2;
  return dx * dx + dy * dy;
}

__device__ __forceinline__ constexpr int TIDX(int i, int j) {
  return i * 9 - i * (i - 1) / 2 + (j - i);
}

// f32 packed upper-tri AtA accumulation for one point (both DLT rows), weight w.
__device__ __forceinline__ void accum_packed_f32(float* ata, float w, float x1,
                                                 float y1, float x2, float y2) {
  const int ia[6] = {3, 4, 5, 6, 7, 8};
  const int ib[6] = {0, 1, 2, 6, 7, 8};
  float va[6] = {-x1, -y1, -1.0f, x1 * y2, y1 * y2, y2};
  float vb[6] = {x1, y1, 1.0f, -x1 * x2, -y1 * x2, -x2};
#pragma unroll
  for (int u = 0; u < 6; u++) {
    float wa = w * va[u];
#pragma unroll
    for (int v = u; v < 6; v++) ata[TIDX(ia[u], ia[v])] += wa * va[v];
  }
#pragma unroll
  for (int u = 0; u < 6; u++) {
    float wb = w * vb[u];
#pragma unroll
    for (int v = u; v < 6; v++) ata[TIDX(ib[u], ib[v])] += wb * vb[v];
  }
}

// f64 full-matrix (upper) accumulation, weight 1 (phase-1 minimal fit).
__device__ __forceinline__ void accum_full_f64(double M[9][9], double x1,
                                               double y1, double x2, double y2) {
  const int ia[6] = {3, 4, 5, 6, 7, 8};
  const int ib[6] = {0, 1, 2, 6, 7, 8};
  double va[6] = {-x1, -y1, -1.0, x1 * y2, y1 * y2, y2};
  double vb[6] = {x1, y1, 1.0, -x1 * x2, -y1 * x2, -x2};
#pragma unroll
  for (int u = 0; u < 6; u++)
#pragma unroll
    for (int v = u; v < 6; v++) M[ia[u]][ia[v]] += va[u] * va[v];
#pragma unroll
  for (int u = 0; u < 6; u++)
#pragma unroll
    for (int v = u; v < 6; v++) M[ib[u]][ib[v]] += vb[u] * vb[v];
}

// Smallest-eigenvector of symmetric 9x9 (upper triangle filled), in-place.
// Ridge-regularized Cholesky + 3 inverse-iteration steps. Destroys M.
__device__ __forceinline__ void solve_null9(double M[9][9], double h[9]) {
  double tr = 0.0;
#pragma unroll
  for (int i = 0; i < 9; i++) {
    tr += M[i][i];
#pragma unroll
    for (int j = i + 1; j < 9; j++) M[j][i] = M[i][j];
  }
  double ridge = tr * 1e-12 + 1e-30;
#pragma unroll
  for (int i = 0; i < 9; i++) M[i][i] += ridge;
  // Cholesky (lower, in place)
#pragma unroll
  for (int j = 0; j < 9; j++) {
    double d = M[j][j];
#pragma unroll
    for (int k = 0; k < j; k++) d -= M[j][k] * M[j][k];
    d = (d > 1e-280) ? d : 1e-280;
    double dj = sqrt(d);
    M[j][j] = dj;
    double inv = 1.0 / dj;
#pragma unroll
    for (int i = j + 1; i < 9; i++) {
      double v = M[i][j];
#pragma unroll
      for (int k = 0; k < j; k++) v -= M[i][k] * M[j][k];
      M[i][j] = v * inv;
    }
  }
  double x[9] = {1, 1, 1, 1, 1, 1, 1, 1, 1};
#pragma unroll
  for (int it = 0; it < 3; ++it) {
#pragma unroll
    for (int i = 0; i < 9; i++) {
      double v = x[i];
#pragma unroll
      for (int k = 0; k < i; k++) v -= M[i][k] * x[k];
      x[i] = v / M[i][i];
    }
#pragma unroll
    for (int i = 8; i >= 0; i--) {
      double v = x[i];
#pragma unroll
      for (int k = i + 1; k < 9; k++) v -= M[k][i] * x[k];
      x[i] = v / M[i][i];
    }
    double mx = fabs(x[0]);
#pragma unroll
    for (int i = 1; i < 9; i++) mx = fmax(mx, fabs(x[i]));
    double r = 1.0 / mx;
#pragma unroll
    for (int i = 0; i < 9; i++) x[i] *= r;
  }
#pragma unroll
  for (int i = 0; i < 9; i++) h[i] = x[i];
}

// H = inv(T2) * Hhat * T1, then divide by (H[2][2] + 1e-8).
__device__ __forceinline__ void denorm9(const double hh[9], double mx1,
                                        double my1, double s1, double mx2,
                                        double my2, double s2, float out[9]) {
  double is2 = 1.0 / s2;
  double g0 = is2 * hh[0] + mx2 * hh[6];
  double g1 = is2 * hh[1] + mx2 * hh[7];
  double g2 = is2 * hh[2] + mx2 * hh[8];
  double g3 = is2 * hh[3] + my2 * hh[6];
  double g4 = is2 * hh[4] + my2 * hh[7];
  double g5 = is2 * hh[5] + my2 * hh[8];
  double g6 = hh[6], g7 = hh[7], g8 = hh[8];
  double a = -s1 * mx1, b = -s1 * my1;
  double H0 = s1 * g0, H1 = s1 * g1, H2 = a * g0 + b * g1 + g2;
  double H3 = s1 * g3, H4 = s1 * g4, H5 = a * g3 + b * g4 + g5;
  double H6 = s1 * g6, H7 = s1 * g7, H8 = a * g6 + b * g7 + g8;
  double inv = 1.0 / (H8 + 1e-8);
  out[0] = (float)(H0 * inv);
  out[1] = (float)(H1 * inv);
  out[2] = (float)(H2 * inv);
  out[3] = (float)(H3 * inv);
  out[4] = (float)(H4 * inv);
  out[5] = (float)(H5 * inv);
  out[6] = (float)(H6 * inv);
  out[7] = (float)(H7 * inv);
  out[8] = (float)(H8 * inv);
}

// ---------------------------------------------------------------------------
// K1: one block per sample. Thread 0: 4-point DLT fit (f64). All 256 threads:
// score against all N points. Writes models[b*9..] and scores[b].
__global__ __launch_bounds__(256, 2) void k_fit_score(
    const float2* __restrict__ kp1, const float2* __restrict__ kp2,
    const int* __restrict__ idxs, int N, float* __restrict__ models,
    float* __restrict__ scores) {
  __shared__ float sH[9];
  __shared__ int sValid;
  __shared__ int sCnt[4];
  const int b = blockIdx.x;
  const int t = threadIdx.x;

  if (t == 0) {
    double X1[4], Y1[4], X2[4], Y2[4];
#pragma unroll
    for (int k = 0; k < 4; k++) {
      int id = idxs[b * 4 + k];
      float2 a = kp1[id];
      float2 c = kp2[id];
      X1[k] = a.x; Y1[k] = a.y; X2[k] = c.x; Y2[k] = c.y;
    }
    // sample validity: consistent orientation of 4 triplets
    const int t0[4] = {0, 0, 0, 1};
    const int t1[4] = {1, 2, 1, 2};
    const int t2[4] = {2, 3, 3, 3};
    bool vs = true;
#pragma unroll
    for (int q = 0; q < 4; q++) {
      int i0 = t0[q], i1 = t1[q], i2 = t2[q];
      double d1 = (X1[i1] - X1[i0]) * (Y1[i2] - Y1[i0]) -
                  (X1[i2] - X1[i0]) * (Y1[i1] - Y1[i0]);
      double d2 = (X2[i1] - X2[i0]) * (Y2[i2] - Y2[i0]) -
                  (X2[i2] - X2[i0]) * (Y2[i1] - Y2[i0]);
      int sg1 = (d1 > 0.0) ? 1 : ((d1 < 0.0) ? -1 : 0);
      int sg2 = (d2 > 0.0) ? 1 : ((d2 < 0.0) ? -1 : 0);
      vs = vs && (sg1 == sg2);
    }
    // normalize 4 points
    double mx1 = (X1[0] + X1[1] + X1[2] + X1[3]) * 0.25;
    double my1 = (Y1[0] + Y1[1] + Y1[2] + Y1[3]) * 0.25;
    double mx2 = (X2[0] + X2[1] + X2[2] + X2[3]) * 0.25;
    double my2 = (Y2[0] + Y2[1] + Y2[2] + Y2[3]) * 0.25;
    double n1 = 0.0, n2 = 0.0;
#pragma unroll
    for (int k = 0; k < 4; k++) {
      double dx = X1[k] - mx1, dy = Y1[k] - my1;
      n1 += sqrt(dx * dx + dy * dy);
      dx = X2[k] - mx2; dy = Y2[k] - my2;
      n2 += sqrt(dx * dx + dy * dy);
    }
    double s1 = sqrt(2.0) / (n1 * 0.25 + 1e-8);
    double s2 = sqrt(2.0) / (n2 * 0.25 + 1e-8);
    double M[9][9];
#pragma unroll
    for (int i = 0; i < 9; i++)
#pragma unroll
      for (int j = 0; j < 9; j++) M[i][j] = 0.0;
#pragma unroll
    for (int k = 0; k < 4; k++)
      accum_full_f64(M, (X1[k] - mx1) * s1, (Y1[k] - my1) * s1,
                     (X2[k] - mx2) * s2, (Y2[k] - my2) * s2);
    double hh[9];
    solve_null9(M, hh);
    float Hf[9];
    denorm9(hh, mx1, my1, s1, mx2, my2, s2, Hf);
    bool vm =
        fminf(fminf(fabsf(Hf[0]), fabsf(Hf[4])), fabsf(Hf[8])) > 1e-4f;
#pragma unroll
    for (int j = 0; j < 9; j++) sH[j] = Hf[j];
    sValid = (vs && vm) ? 1 : 0;
  }
  __syncthreads();

  float h[9];
#pragma unroll
  for (int j = 0; j < 9; j++) h[j] = sH[j];
  int cnt = 0;
  for (int i = t; i < N; i += 256) {
    float2 a = kp1[i];
    float2 c = kp2[i];
    cnt += (sq_err9(h, a.x, a.y, c.x, c.y) <= 2.0f) ? 1 : 0;
  }
#pragma unroll
  for (int off = 32; off; off >>= 1) cnt += __shfl_down(cnt, off);
  if ((t & 63) == 0) sCnt[t >> 6] = cnt;
  __syncthreads();
  if (t == 0) {
    int tot = sCnt[0] + sCnt[1] + sCnt[2] + sCnt[3];
    scores[b] = sValid ? (float)tot : -1.0f;
#pragma unroll
    for (int j = 0; j < 9; j++) models[b * 9 + j] = sH[j];
  }
}

// ---------------------------------------------------------------------------
// K2: argmax over scores (tie-break: smallest index), and the full-set
// normalization parameters (f64) used by every polish DLT.
__global__ __launch_bounds__(1024) void k_select(
    const float2* __restrict__ kp1, const float2* __restrict__ kp2, int N,
    int B, const float* __restrict__ scores, Hdr* __restrict__ hdr) {
  const int t = threadIdx.x;
  const int lane = t & 63, wid = t >> 6;
  __shared__ float rs[1024];
  __shared__ int ri[1024];

  float bs = -2.0f;
  int bi = 0x7fffffff;
  for (int i = t; i < B; i += 1024) {
    float s = scores[i];
    if (s > bs || (s == bs && i < bi)) { bs = s; bi = i; }
  }
  rs[t] = bs;
  ri[t] = bi;
  __syncthreads();
  for (int off = 512; off; off >>= 1) {
    if (t < off) {
      float s = rs[t + off];
      int i2 = ri[t + off];
      if (s > rs[t] || (s == rs[t] && i2 < ri[t])) { rs[t] = s; ri[t] = i2; }
    }
    __syncthreads();
  }
  if (t == 0) {
    hdr->best_idx = ri[0];
    hdr->best_score = rs[0];
  }

  // means (f64)
  __shared__ double red[16][4];
  __shared__ double mb[4];
  double sx1 = 0, sy1 = 0, sx2 = 0, sy2 = 0;
  for (int i = t; i < N; i += 1024) {
    float2 a = kp1[i];
    float2 c = kp2[i];
    sx1 += a.x; sy1 += a.y; sx2 += c.x; sy2 += c.y;
  }
#pragma unroll
  for (int off = 32; off; off >>= 1) {
    sx1 += __shfl_down(sx1, off);
    sy1 += __shfl_down(sy1, off);
    sx2 += __shfl_down(sx2, off);
    sy2 += __shfl_down(sy2, off);
  }
  if (lane == 0) {
    red[wid][0] = sx1; red[wid][1] = sy1; red[wid][2] = sx2; red[wid][3] = sy2;
  }
  __syncthreads();
  if (t == 0) {
    double a = 0, b2 = 0, c = 0, d = 0;
    for (int w2 = 0; w2 < 16; w2++) {
      a += red[w2][0]; b2 += red[w2][1]; c += red[w2][2]; d += red[w2][3];
    }
    mb[0] = a / N; mb[1] = b2 / N; mb[2] = c / N; mb[3] = d / N;
  }
  __syncthreads();
  double mx1 = mb[0], my1 = mb[1], mx2 = mb[2], my2 = mb[3];
  double sn1 = 0, sn2 = 0;
  for (int i = t; i < N; i += 1024) {
    float2 a = kp1[i];
    float2 c = kp2[i];
    double dx = a.x - mx1, dy = a.y - my1;
    sn1 += sqrt(dx * dx + dy * dy);
    dx = c.x - mx2; dy = c.y - my2;
    sn2 += sqrt(dx * dx + dy * dy);
  }
#pragma unroll
  for (int off = 32; off; off >>= 1) {
    sn1 += __shfl_down(sn1, off);
    sn2 += __shfl_down(sn2, off);
  }
  __syncthreads();
  if (lane == 0) { red[wid][0] = sn1; red[wid][1] = sn2; }
  __syncthreads();
  if (t == 0) {
    double a = 0, b2 = 0;
    for (int w2 = 0; w2 < 16; w2++) { a += red[w2][0]; b2 += red[w2][1]; }
    hdr->nrm[0] = mx1;
    hdr->nrm[1] = my1;
    hdr->nrm[2] = sqrt(2.0) / (a / N + 1e-8);
    hdr->nrm[3] = mx2;
    hdr->nrm[4] = my2;
    hdr->nrm[5] = sqrt(2.0) / (b2 / N + 1e-8);
  }
}

// ---------------------------------------------------------------------------
// K3: single persistent block; 5 LO iterations x 5 weighted DLTs over all N.
#define K3_T 512
#define PPT 20  // ceil(10000/512)

__global__ __launch_bounds__(512) void k_lo(const float2* __restrict__ kp1,
                                            const float2* __restrict__ kp2,
                                            int N,
                                            const float* __restrict__ models,
                                            const Hdr* __restrict__ hdr,
                                            float* __restrict__ out,
                                            int out_size) {
  const int t = threadIdx.x;
  const int lane = t & 63, wid = t >> 6;
  __shared__ double sAtA[45];
  __shared__ float sWred[8][45];
  __shared__ float sHcur[9];
  __shared__ float sHpol[9];
  __shared__ float sScLo;
  __shared__ int sCnt[8];
  __shared__ double sPar[6];
  __shared__ float sAccept;

  if (t == 0) {
    int bi = hdr->best_idx;
#pragma unroll
    for (int j = 0; j < 9; j++) sHcur[j] = models[bi * 9 + j];
    sAccept = hdr->best_score;
#pragma unroll
    for (int j = 0; j < 6; j++) sPar[j] = hdr->nrm[j];
  }
  __syncthreads();
  const bool accept = sAccept > 4.0f;  // score > MIN_SAMPLE
  if (!accept) {
    for (int i = t; i < out_size; i += K3_T) out[i] = 0.0f;
    return;
  }
  const float mx1 = (float)sPar[0], my1 = (float)sPar[1], s1 = (float)sPar[2];
  const float mx2 = (float)sPar[3], my2 = (float)sPar[4], s2 = (float)sPar[5];

  // initial inlier mask from the phase-1 best model
  float hc[9];
#pragma unroll
  for (int j = 0; j < 9; j++) hc[j] = sHcur[j];
  unsigned int il = 0u;
  for (int p = 0; p < PPT; p++) {
    int i = p * K3_T + t;
    if (i < N) {
      float2 a = kp1[i];
      float2 c = kp2[i];
      if (sq_err9(hc, a.x, a.y, c.x, c.y) <= 2.0f) il |= (1u << p);
    }
  }
  float sc = sAccept;

  for (int lo = 0; lo < 5; ++lo) {
    // polish_model: 5 DLTs; base weight = il mask, times soft weight for j>0
    for (int j = 0; j < 5; ++j) {
      float hp[9];
      if (j > 0) {
#pragma unroll
        for (int q = 0; q < 9; q++) hp[q] = sHpol[q];
      }
      float acc[45];
#pragma unroll
      for (int k = 0; k < 45; k++) acc[k] = 0.0f;
      for (int p = 0; p < PPT; p++) {
        int i = p * K3_T + t;
        if (i < N) {
          float w = ((il >> p) & 1u) ? 1.0f : 0.0f;
          if (w != 0.0f) {
            float2 a = kp1[i];
            float2 c = kp2[i];
            if (j > 0) {
              float e = sq_err9(hp, a.x, a.y, c.x, c.y);
              w = expf(-sqrtf(fmaxf(e, 0.0f)) / 18.0f);
            }
            float xn1 = (a.x - mx1) * s1, yn1 = (a.y - my1) * s1;
            float xn2 = (c.x - mx2) * s2, yn2 = (c.y - my2) * s2;
            accum_packed_f32(acc, w, xn1, yn1, xn2, yn2);
          }
        }
      }
      // block reduction of 45 accumulators
#pragma unroll
      for (int k = 0; k < 45; k++) {
        float v = acc[k];
#pragma unroll
        for (int off = 32; off; off >>= 1) v += __shfl_down(v, off);
        if (lane == 0) sWred[wid][k] = v;
      }
      __syncthreads();
      if (t < 45) {
        double s = 0.0;
#pragma unroll
        for (int w2 = 0; w2 < 8; w2++) s += (double)sWred[w2][t];
        sAtA[t] = s;
      }
      __syncthreads();
      if (t == 0) {
        double M[9][9];
        int k = 0;
#pragma unroll
        for (int i2 = 0; i2 < 9; i2++)
#pragma unroll
          for (int j2 = i2; j2 < 9; j2++) M[i2][j2] = sAtA[k++];
        double hh[9];
        solve_null9(M, hh);
        float ho[9];
        denorm9(hh, sPar[0], sPar[1], sPar[2], sPar[3], sPar[4], sPar[5], ho);
#pragma unroll
        for (int q = 0; q < 9; q++) sHpol[q] = ho[q];
      }
      __syncthreads();
    }
    // score m_lo
    float hl[9];
#pragma unroll
    for (int q = 0; q < 9; q++) hl[q] = sHpol[q];
    unsigned int il_lo = 0u;
    int cnt = 0;
    for (int p = 0; p < PPT; p++) {
      int i = p * K3_T + t;
      if (i < N) {
        float2 a = kp1[i];
        float2 c = kp2[i];
        if (sq_err9(hl, a.x, a.y, c.x, c.y) <= 2.0f) {
          il_lo |= (1u << p);
          cnt++;
        }
      }
    }
#pragma unroll
    for (int off = 32; off; off >>= 1) cnt += __shfl_down(cnt, off);
    if (lane == 0) sCnt[wid] = cnt;
    __syncthreads();
    if (t == 0) {
      int tot = 0;
#pragma unroll
      for (int w2 = 0; w2 < 8; w2++) tot += sCnt[w2];
      sScLo = (float)tot;
    }
    __syncthreads();
    float sc_lo = sScLo;
    if (sc_lo > sc) {  // uniform across block
      il = il_lo;
      sc = sc_lo;
      if (t == 0) {
#pragma unroll
        for (int q = 0; q < 9; q++) sHcur[q] = sHpol[q];
      }
    }
    __syncthreads();
  }

  // write outputs
  if (t < 9 && t < out_size) out[t] = sHcur[t];
  for (int p = 0; p < PPT; p++) {
    int i = p * K3_T + t;
    if (i < N && (9 + i) < out_size)
      out[9 + i] = ((il >> p) & 1u) ? 1.0f : 0.0f;
  }
  for (int i = 9 + N + t; i < out_size; i += K3_T) out[i] = 0.0f;
}

// ---------------------------------------------------------------------------
extern "C" void kernel_launch(void* const* d_in, const int* in_sizes, int n_in,
                              void* d_out, int out_size, void* d_ws,
                              size_t ws_size, hipStream_t stream) {
  (void)n_in;
  (void)ws_size;
  const float2* kp1 = (const float2*)d_in[0];
  const float2* kp2 = (const float2*)d_in[1];
  const int* idxs = (const int*)d_in[2];
  const int N = in_sizes[0] / 2;
  const int B = in_sizes[2] / 4;

  float* models = (float*)d_ws;
  float* scores = models + (size_t)B * 9;
  size_t off = (((size_t)B * 10 * sizeof(float)) + 15) & ~(size_t)15;
  Hdr* hdr = (Hdr*)((char*)d_ws + off);
  float* outf = (float*)d_out;

  k_fit_score<<<B, 256, 0, stream>>>(kp1, kp2, idxs, N, models, scores);
  k_select<<<1, 1024, 0, stream>>>(kp1, kp2, N, B, scores, hdr);
  k_lo<<<1, K3_T, 0, stream>>>(kp1, kp2, N, models, hdr, outf, out_size);
}

// Round 6
// 644.219 us; speedup vs baseline: 1.0592x; 1.0592x over previous
//
#include <hip/hip_runtime.h>
#include <math.h>

// RANSAC homography (kornia-style) for MI355X, round 6 (= R3 source, third
// resubmit; broker timeouts R3/R4/R5 — kernel has never run).
// R2 post-mortem: __shfl inside `if (lane==0)` reads inactive lanes ->
// garbage (EXEC-masked ds_bpermute). All models got invalidated, output was
// the zero path (absmax 10.0 == largest H_gt entry). Fix: gather the
// solution vector at FULL EXEC, then branch for the serial denorm.

struct Hdr {
  int best_idx;
  float best_score;
  int pad0, pad1;
  double nrm[6]; // mx1, my1, s1, mx2, my2, s2
};

__device__ __host__ constexpr int TRI6(int u, int v) {
  return u * 6 - u * (u - 1) / 2 + (v - u);
}

__device__ __forceinline__ float sq_err9(const float h[9], float x1, float y1,
                                         float x2, float y2) {
  float px = h[0] * x1 + h[1] * y1 + h[2];
  float py = h[3] * x1 + h[4] * y1 + h[5];
  float pz = h[6] * x1 + h[7] * y1 + h[8];
  float s  = (fabsf(pz) > 1e-8f) ? (1.0f / pz) : 1.0f;
  float dx = px * s - x2;
  float dy = py * s - y2;
  return dx * dx + dy * dy;
}

__device__ __forceinline__ double sel9d(const double* a, int k) {
  double d = a[0];
  d = (k == 1) ? a[1] : d;
  d = (k == 2) ? a[2] : d;
  d = (k == 3) ? a[3] : d;
  d = (k == 4) ? a[4] : d;
  d = (k == 5) ? a[5] : d;
  d = (k == 6) ? a[6] : d;
  d = (k == 7) ? a[7] : d;
  d = (k == 8) ? a[8] : d;
  return d;
}
__device__ __forceinline__ double sel4d(const double* a, int k) {
  double d = a[0];
  d = (k == 1) ? a[1] : d;
  d = (k == 2) ? a[2] : d;
  d = (k == 3) ? a[3] : d;
  return d;
}

// ---------------------------------------------------------------------------
// Wave-parallel smallest-eigenvector solve of symmetric 9x9.
// One FULL wave executes (no divergence around calls). Lane i (i<9) holds row
// i of M in r[0..8]. Ridge + row-per-lane Cholesky + 3 inverse-iteration
// steps. On return lane k<9 holds x[k] in *xs.
__device__ __forceinline__ void wave_solve9(double r[9], int lane, double* xs) {
  double dself = sel9d(r, lane);
  double tr = (lane < 9) ? dself : 0.0;
#pragma unroll
  for (int m = 1; m <= 8; m <<= 1) tr += __shfl_xor(tr, m);
  double ridge = tr * 1e-12 + 1e-30;
#pragma unroll
  for (int k = 0; k < 9; k++)
    if (lane == k) r[k] += ridge;

  double u[9];  // u[k] = L[k][lane] (for back-solve)
#pragma unroll
  for (int k = 0; k < 9; k++) u[k] = 0.0;
  double invd = 0.0;

#pragma unroll
  for (int j = 0; j < 9; j++) {
    double dj = __shfl(r[j], j);
    dj = (dj > 1e-280) ? dj : 1e-280;
    double is = rsqrt(dj);
    double s = dj * is;
    double Lij = r[j] * is;  // valid for lane > j
    if (lane == j) { Lij = s; invd = is; }
    r[j] = Lij;
    double c[9];
#pragma unroll
    for (int k = j; k < 9; k++) c[k] = __shfl(r[j], k);  // column j of L
#pragma unroll
    for (int k = j; k < 9; k++)
      if (lane == j) u[k] = c[k];
    if (lane > j) {
#pragma unroll
      for (int k = j + 1; k < 9; k++) r[k] -= Lij * c[k];
    }
  }

  double x = 1.0;
#pragma unroll
  for (int it = 0; it < 3; ++it) {
    // forward: L y = x
    double acc = x;
    double y = 0.0;
#pragma unroll
    for (int k = 0; k < 9; k++) {
      double yk = __shfl(acc * invd, k);
      if (lane == k) y = yk;
      if (lane > k) acc -= r[k] * yk;
    }
    // backward: L^T x = y
    acc = y;
#pragma unroll
    for (int k = 8; k >= 0; k--) {
      double xk = __shfl(acc * invd, k);
      if (lane == k) x = xk;
      if (lane < k) acc -= u[k] * xk;
    }
    double m2 = (lane < 9) ? fabs(x) : 0.0;
#pragma unroll
    for (int m = 1; m <= 8; m <<= 1) m2 = fmax(m2, __shfl_xor(m2, m));
    x *= 1.0 / m2;
  }
  *xs = x;
}

// H = inv(T2) * Hhat * T1, then divide by (H[2][2] + 1e-8). Serial, static.
__device__ __forceinline__ void denorm9(const double hh[9], double mx1,
                                        double my1, double s1, double mx2,
                                        double my2, double s2, float out[9]) {
  double is2 = 1.0 / s2;
  double g0 = is2 * hh[0] + mx2 * hh[6];
  double g1 = is2 * hh[1] + mx2 * hh[7];
  double g2 = is2 * hh[2] + mx2 * hh[8];
  double g3 = is2 * hh[3] + my2 * hh[6];
  double g4 = is2 * hh[4] + my2 * hh[7];
  double g5 = is2 * hh[5] + my2 * hh[8];
  double g6 = hh[6], g7 = hh[7], g8 = hh[8];
  double a = -s1 * mx1, b = -s1 * my1;
  double H0 = s1 * g0, H1 = s1 * g1, H2 = a * g0 + b * g1 + g2;
  double H3 = s1 * g3, H4 = s1 * g4, H5 = a * g3 + b * g4 + g5;
  double H6 = s1 * g6, H7 = s1 * g7, H8 = a * g6 + b * g7 + g8;
  double inv = 1.0 / (H8 + 1e-8);
  out[0] = (float)(H0 * inv);
  out[1] = (float)(H1 * inv);
  out[2] = (float)(H2 * inv);
  out[3] = (float)(H3 * inv);
  out[4] = (float)(H4 * inv);
  out[5] = (float)(H5 * inv);
  out[6] = (float)(H6 * inv);
  out[7] = (float)(H7 * inv);
  out[8] = (float)(H8 * inv);
}

// Map (i,j) [i<=j] of the 9x9 AtA to the two 6x6 triangle blocks.
// A-block = rows/cols {3..8}, B-block = rows/cols {0,1,2,6,7,8}.
__device__ __forceinline__ double m_entry(const double* CA, const double* CB,
                                          int i, int j) {
  double s = 0.0;
  if (i >= 3) s += CA[TRI6(i - 3, j - 3)];
  if ((i < 3 || i >= 6) && (j < 3 || j >= 6)) {
    int ui = (i < 3) ? i : i - 3;
    int vj = (j < 3) ? j : j - 3;
    s += CB[TRI6(ui, vj)];
  }
  return s;
}

// ---------------------------------------------------------------------------
// K1: one 64-thread block (one wave) per sample.
__global__ __launch_bounds__(64, 2) void k_fit_score(
    const float2* __restrict__ kp1, const float2* __restrict__ kp2,
    const int* __restrict__ idxs, int N, float* __restrict__ models,
    float* __restrict__ scores) {
  __shared__ double sA8[8 * 9];
  __shared__ float sH[9];
  const int b = blockIdx.x;
  const int lane = threadIdx.x;

  double X1[4], Y1[4], X2[4], Y2[4];
#pragma unroll
  for (int k = 0; k < 4; k++) {
    int id = idxs[b * 4 + k];
    float2 a = kp1[id];
    float2 c = kp2[id];
    X1[k] = a.x; Y1[k] = a.y; X2[k] = c.x; Y2[k] = c.y;
  }
  const int t0[4] = {0, 0, 0, 1};
  const int t1[4] = {1, 2, 1, 2};
  const int t2[4] = {2, 3, 3, 3};
  bool vs = true;
#pragma unroll
  for (int q = 0; q < 4; q++) {
    int i0 = t0[q], i1 = t1[q], i2 = t2[q];
    double d1 = (X1[i1] - X1[i0]) * (Y1[i2] - Y1[i0]) -
                (X1[i2] - X1[i0]) * (Y1[i1] - Y1[i0]);
    double d2 = (X2[i1] - X2[i0]) * (Y2[i2] - Y2[i0]) -
                (X2[i2] - X2[i0]) * (Y2[i1] - Y2[i0]);
    int sg1 = (d1 > 0.0) ? 1 : ((d1 < 0.0) ? -1 : 0);
    int sg2 = (d2 > 0.0) ? 1 : ((d2 < 0.0) ? -1 : 0);
    vs = vs && (sg1 == sg2);
  }
  double mx1 = (X1[0] + X1[1] + X1[2] + X1[3]) * 0.25;
  double my1 = (Y1[0] + Y1[1] + Y1[2] + Y1[3]) * 0.25;
  double mx2 = (X2[0] + X2[1] + X2[2] + X2[3]) * 0.25;
  double my2 = (Y2[0] + Y2[1] + Y2[2] + Y2[3]) * 0.25;
  double n1 = 0.0, n2 = 0.0;
#pragma unroll
  for (int k = 0; k < 4; k++) {
    double dx = X1[k] - mx1, dy = Y1[k] - my1;
    n1 += sqrt(dx * dx + dy * dy);
    dx = X2[k] - mx2; dy = Y2[k] - my2;
    n2 += sqrt(dx * dx + dy * dy);
  }
  double s1 = sqrt(2.0) / (n1 * 0.25 + 1e-8);
  double s2 = sqrt(2.0) / (n2 * 0.25 + 1e-8);

  if (lane < 8) {
    int k = lane >> 1;
    double xn1 = (sel4d(X1, k) - mx1) * s1;
    double yn1 = (sel4d(Y1, k) - my1) * s1;
    double xn2 = (sel4d(X2, k) - mx2) * s2;
    double yn2 = (sel4d(Y2, k) - my2) * s2;
    bool odd = (lane & 1) != 0;
    sA8[lane * 9 + 0] = odd ? xn1 : 0.0;
    sA8[lane * 9 + 1] = odd ? yn1 : 0.0;
    sA8[lane * 9 + 2] = odd ? 1.0 : 0.0;
    sA8[lane * 9 + 3] = odd ? 0.0 : -xn1;
    sA8[lane * 9 + 4] = odd ? 0.0 : -yn1;
    sA8[lane * 9 + 5] = odd ? 0.0 : -1.0;
    sA8[lane * 9 + 6] = odd ? -xn2 * xn1 : yn2 * xn1;
    sA8[lane * 9 + 7] = odd ? -xn2 * yn1 : yn2 * yn1;
    sA8[lane * 9 + 8] = odd ? -xn2 : yn2;
  }
  __syncthreads();

  double r[9];
  {
    int i = (lane < 9) ? lane : 0;
    double ai[8];
#pragma unroll
    for (int l = 0; l < 8; l++) ai[l] = sA8[l * 9 + i];
#pragma unroll
    for (int j = 0; j < 9; j++) {
      double s = 0.0;
#pragma unroll
      for (int l = 0; l < 8; l++) s += ai[l] * sA8[l * 9 + j];
      r[j] = s;
    }
  }
  double xs;
  wave_solve9(r, lane, &xs);

  // FULL-EXEC gather of the solution vector (fix for R2's EXEC-masked shfl)
  double hh[9];
#pragma unroll
  for (int k = 0; k < 9; k++) hh[k] = __shfl(xs, k);

  bool valid = vs;
  if (lane == 0) {
    float Hf[9];
    denorm9(hh, mx1, my1, s1, mx2, my2, s2, Hf);
    bool vm = fminf(fminf(fabsf(Hf[0]), fabsf(Hf[4])), fabsf(Hf[8])) > 1e-4f;
    valid = vs && vm;
#pragma unroll
    for (int j = 0; j < 9; j++) sH[j] = Hf[j];
  }
  __syncthreads();

  float h[9];
#pragma unroll
  for (int j = 0; j < 9; j++) h[j] = sH[j];
  int cnt = 0;
  for (int i = lane; i < N; i += 64) {
    float2 a = kp1[i];
    float2 c = kp2[i];
    cnt += (sq_err9(h, a.x, a.y, c.x, c.y) <= 2.0f) ? 1 : 0;
  }
#pragma unroll
  for (int off = 32; off; off >>= 1) cnt += __shfl_down(cnt, off);
  if (lane == 0) {
    scores[b] = valid ? (float)cnt : -1.0f;
#pragma unroll
    for (int j = 0; j < 9; j++) models[b * 9 + j] = sH[j];
  }
}

// ---------------------------------------------------------------------------
// K2: argmax over scores + full-set normalization parameters.
__global__ __launch_bounds__(1024) void k_select(
    const float2* __restrict__ kp1, const float2* __restrict__ kp2, int N,
    int B, const float* __restrict__ scores, Hdr* __restrict__ hdr) {
  const int t = threadIdx.x;
  const int lane = t & 63, wid = t >> 6;
  __shared__ float rs[1024];
  __shared__ int ri[1024];

  float bs = -2.0f;
  int bi = 0x7fffffff;
  for (int i = t; i < B; i += 1024) {
    float s = scores[i];
    if (s > bs || (s == bs && i < bi)) { bs = s; bi = i; }
  }
  rs[t] = bs;
  ri[t] = bi;
  __syncthreads();
  for (int off = 512; off; off >>= 1) {
    if (t < off) {
      float s = rs[t + off];
      int i2 = ri[t + off];
      if (s > rs[t] || (s == rs[t] && i2 < ri[t])) { rs[t] = s; ri[t] = i2; }
    }
    __syncthreads();
  }
  if (t == 0) {
    hdr->best_idx = ri[0];
    hdr->best_score = rs[0];
  }

  __shared__ double red[16][4];
  __shared__ double mb[4];
  double sx1 = 0, sy1 = 0, sx2 = 0, sy2 = 0;
  for (int i = t; i < N; i += 1024) {
    float2 a = kp1[i];
    float2 c = kp2[i];
    sx1 += a.x; sy1 += a.y; sx2 += c.x; sy2 += c.y;
  }
#pragma unroll
  for (int off = 32; off; off >>= 1) {
    sx1 += __shfl_down(sx1, off);
    sy1 += __shfl_down(sy1, off);
    sx2 += __shfl_down(sx2, off);
    sy2 += __shfl_down(sy2, off);
  }
  if (lane == 0) {
    red[wid][0] = sx1; red[wid][1] = sy1; red[wid][2] = sx2; red[wid][3] = sy2;
  }
  __syncthreads();
  if (t == 0) {
    double a = 0, b2 = 0, c = 0, d = 0;
    for (int w2 = 0; w2 < 16; w2++) {
      a += red[w2][0]; b2 += red[w2][1]; c += red[w2][2]; d += red[w2][3];
    }
    mb[0] = a / N; mb[1] = b2 / N; mb[2] = c / N; mb[3] = d / N;
  }
  __syncthreads();
  double mx1 = mb[0], my1 = mb[1], mx2 = mb[2], my2 = mb[3];
  double sn1 = 0, sn2 = 0;
  for (int i = t; i < N; i += 1024) {
    float2 a = kp1[i];
    float2 c = kp2[i];
    double dx = a.x - mx1, dy = a.y - my1;
    sn1 += sqrt(dx * dx + dy * dy);
    dx = c.x - mx2; dy = c.y - my2;
    sn2 += sqrt(dx * dx + dy * dy);
  }
#pragma unroll
  for (int off = 32; off; off >>= 1) {
    sn1 += __shfl_down(sn1, off);
    sn2 += __shfl_down(sn2, off);
  }
  __syncthreads();
  if (lane == 0) { red[wid][0] = sn1; red[wid][1] = sn2; }
  __syncthreads();
  if (t == 0) {
    double a = 0, b2 = 0;
    for (int w2 = 0; w2 < 16; w2++) { a += red[w2][0]; b2 += red[w2][1]; }
    hdr->nrm[0] = mx1;
    hdr->nrm[1] = my1;
    hdr->nrm[2] = sqrt(2.0) / (a / N + 1e-8);
    hdr->nrm[3] = mx2;
    hdr->nrm[4] = my2;
    hdr->nrm[5] = sqrt(2.0) / (b2 / N + 1e-8);
  }
}

// ---------------------------------------------------------------------------
// K3: single persistent 512-thread block; 5 LO iterations x 5 weighted DLTs.
#define K3_T 512
#define PPT 20  // ceil(10000/512)

__global__ __launch_bounds__(512, 2) void k_lo(const float2* __restrict__ kp1,
                                               const float2* __restrict__ kp2,
                                               int N,
                                               const float* __restrict__ models,
                                               const Hdr* __restrict__ hdr,
                                               float* __restrict__ out,
                                               int out_size) {
  const int t = threadIdx.x;
  const int lane = t & 63, wid = t >> 6;
  __shared__ float sP[K3_T * 42];   // per-thread AtA partials (84 KB)
  __shared__ double sP2[42 * 8];    // per-64-group f64 partials
  __shared__ double sC[42];         // CA = sC[0..20], CB = sC[21..41]
  __shared__ float sHcur[9];
  __shared__ float sHpol[9];
  __shared__ float sScLo;
  __shared__ int sCnt[8];
  __shared__ double sPar[6];
  __shared__ float sAccept;

  if (t == 0) {
    int bi = hdr->best_idx;
#pragma unroll
    for (int j = 0; j < 9; j++) sHcur[j] = models[bi * 9 + j];
    sAccept = hdr->best_score;
#pragma unroll
    for (int j = 0; j < 6; j++) sPar[j] = hdr->nrm[j];
  }
  __syncthreads();
  const bool accept = sAccept > 4.0f;  // score > MIN_SAMPLE
  if (!accept) {
    for (int i = t; i < out_size; i += K3_T) out[i] = 0.0f;
    return;
  }
  const float mx1 = (float)sPar[0], my1 = (float)sPar[1], s1 = (float)sPar[2];
  const float mx2 = (float)sPar[3], my2 = (float)sPar[4], s2 = (float)sPar[5];

  float hc[9];
#pragma unroll
  for (int j = 0; j < 9; j++) hc[j] = sHcur[j];
  unsigned int il = 0u;
  for (int p = 0; p < PPT; p++) {
    int i = p * K3_T + t;
    if (i < N) {
      float2 a = kp1[i];
      float2 c = kp2[i];
      if (sq_err9(hc, a.x, a.y, c.x, c.y) <= 2.0f) il |= (1u << p);
    }
  }
  float sc = sAccept;

  for (int lo = 0; lo < 5; ++lo) {
    for (int j = 0; j < 5; ++j) {
      float hp[9];
      if (j > 0) {
#pragma unroll
        for (int q = 0; q < 9; q++) hp[q] = sHpol[q];
      }
      float accA[21], accB[21];
#pragma unroll
      for (int k = 0; k < 21; k++) { accA[k] = 0.0f; accB[k] = 0.0f; }
      for (int p = 0; p < PPT; p++) {
        int i = p * K3_T + t;
        if (i < N && ((il >> p) & 1u)) {
          float2 a = kp1[i];
          float2 c = kp2[i];
          float w = 1.0f;
          if (j > 0) {
            float e = sq_err9(hp, a.x, a.y, c.x, c.y);
            w = expf(-sqrtf(fmaxf(e, 0.0f)) / 18.0f);
          }
          float xn1 = (a.x - mx1) * s1, yn1 = (a.y - my1) * s1;
          float xn2 = (c.x - mx2) * s2, yn2 = (c.y - my2) * s2;
          float va[6] = {-xn1, -yn1, -1.0f, xn1 * yn2, yn1 * yn2, yn2};
          float vb[6] = {xn1, yn1, 1.0f, -xn1 * xn2, -yn1 * xn2, -xn2};
#pragma unroll
          for (int u = 0; u < 6; u++) {
            float wa = w * va[u];
#pragma unroll
            for (int v = u; v < 6; v++) accA[TRI6(u, v)] += wa * va[v];
          }
#pragma unroll
          for (int u = 0; u < 6; u++) {
            float wb = w * vb[u];
#pragma unroll
            for (int v = u; v < 6; v++) accB[TRI6(u, v)] += wb * vb[v];
          }
        }
      }
#pragma unroll
      for (int k = 0; k < 21; k++) sP[t * 42 + k] = accA[k];
#pragma unroll
      for (int k = 0; k < 21; k++) sP[t * 42 + 21 + k] = accB[k];
      __syncthreads();
      if (t < 336) {
        int col = t % 42, grp = t / 42;
        double s = 0.0;
        int base = grp * 64 * 42 + col;
        for (int i2 = 0; i2 < 64; i2++) s += (double)sP[base + i2 * 42];
        sP2[col * 8 + grp] = s;
      }
      __syncthreads();
      if (t < 42) {
        double s = 0.0;
#pragma unroll
        for (int g = 0; g < 8; g++) s += sP2[t * 8 + g];
        sC[t] = s;
      }
      __syncthreads();
      if (wid == 0) {
        double r[9];
        int i = (lane < 9) ? lane : 0;
#pragma unroll
        for (int jj = 0; jj < 9; jj++) {
          int a2 = (i < jj) ? i : jj;
          int b2 = (i < jj) ? jj : i;
          r[jj] = m_entry(sC, sC + 21, a2, b2);
        }
        double xs;
        wave_solve9(r, lane, &xs);
        // FULL-EXEC (whole wave 0) gather, then lane-0 serial denorm.
        double hh[9];
#pragma unroll
        for (int k = 0; k < 9; k++) hh[k] = __shfl(xs, k);
        if (lane == 0) {
          float ho[9];
          denorm9(hh, sPar[0], sPar[1], sPar[2], sPar[3], sPar[4], sPar[5],
                  ho);
#pragma unroll
          for (int q = 0; q < 9; q++) sHpol[q] = ho[q];
        }
      }
      __syncthreads();
    }
    float hl[9];
#pragma unroll
    for (int q = 0; q < 9; q++) hl[q] = sHpol[q];
    unsigned int il_lo = 0u;
    int cnt = 0;
    for (int p = 0; p < PPT; p++) {
      int i = p * K3_T + t;
      if (i < N) {
        float2 a = kp1[i];
        float2 c = kp2[i];
        if (sq_err9(hl, a.x, a.y, c.x, c.y) <= 2.0f) {
          il_lo |= (1u << p);
          cnt++;
        }
      }
    }
#pragma unroll
    for (int off = 32; off; off >>= 1) cnt += __shfl_down(cnt, off);
    if (lane == 0) sCnt[wid] = cnt;
    __syncthreads();
    if (t == 0) {
      int tot = 0;
#pragma unroll
      for (int w2 = 0; w2 < 8; w2++) tot += sCnt[w2];
      sScLo = (float)tot;
    }
    __syncthreads();
    float sc_lo = sScLo;
    if (sc_lo > sc) {  // uniform across block
      il = il_lo;
      sc = sc_lo;
      if (t == 0) {
#pragma unroll
        for (int q = 0; q < 9; q++) sHcur[q] = sHpol[q];
      }
    }
    __syncthreads();
  }

  if (t < 9 && t < out_size) out[t] = sHcur[t];
  for (int p = 0; p < PPT; p++) {
    int i = p * K3_T + t;
    if (i < N && (9 + i) < out_size)
      out[9 + i] = ((il >> p) & 1u) ? 1.0f : 0.0f;
  }
  for (int i = 9 + N + t; i < out_size; i += K3_T) out[i] = 0.0f;
}

// ---------------------------------------------------------------------------
extern "C" void kernel_launch(void* const* d_in, const int* in_sizes, int n_in,
                              void* d_out, int out_size, void* d_ws,
                              size_t ws_size, hipStream_t stream) {
  (void)n_in;
  (void)ws_size;
  const float2* kp1 = (const float2*)d_in[0];
  const float2* kp2 = (const float2*)d_in[1];
  const int* idxs = (const int*)d_in[2];
  const int N = in_sizes[0] / 2;
  const int B = in_sizes[2] / 4;

  float* models = (float*)d_ws;
  float* scores = models + (size_t)B * 9;
  size_t off = (((size_t)B * 10 * sizeof(float)) + 15) & ~(size_t)15;
  Hdr* hdr = (Hdr*)((char*)d_ws + off);
  float* outf = (float*)d_out;

  k_fit_score<<<B, 64, 0, stream>>>(kp1, kp2, idxs, N, models, scores);
  k_select<<<1, 1024, 0, stream>>>(kp1, kp2, N, B, scores, hdr);
  k_lo<<<1, K3_T, 0, stream>>>(kp1, kp2, N, models, hdr, outf, out_size);
}